// Round 6
// baseline (478.063 us; speedup 1.0000x reference)
//
#include <hip/hip_runtime.h>
#include <hip/hip_bf16.h>

// ---------------------------------------------------------------------------
// BasicCountNet round 6:
//   - fully fused GIN conv: one kernel per conv does CSR gather-agg into the
//     LDS A-tile, MFMA pass1 (W1+b1, ReLU), T1 tile back into same LDS
//     (barrier-isolated), MFMA pass2 (W2+b2), store bf16 / pool.
//     Removes agg kernels + intermediate HBM round-trips (50 MB/conv).
//   - 12 dispatches total.
// ---------------------------------------------------------------------------

#define NQ 64
#define EQ 512
#define ND 50000
#define ED 600000
#define FDIM 128
#define HDIM 256

typedef __attribute__((ext_vector_type(8))) short short8;
typedef __attribute__((ext_vector_type(4))) float f32x4;
typedef __attribute__((ext_vector_type(4))) unsigned short us4;
typedef __attribute__((ext_vector_type(2))) unsigned short us2;

__device__ __forceinline__ unsigned short f2bf(float f) {
    union { float f; unsigned u; } v; v.f = f;
    unsigned r = v.u + 0x7FFF + ((v.u >> 16) & 1);   // RNE
    return (unsigned short)(r >> 16);
}
__device__ __forceinline__ float bf2f(unsigned short u) {
    union { unsigned u; float f; } v; v.u = ((unsigned)u) << 16;
    return v.f;
}

// ---------------- fp32 -> bf16 conversion (both inputs, adjacent dests) ----------------

__global__ void cvt_to_bf16(const float* __restrict__ xd, const float* __restrict__ xq,
                            unsigned short* __restrict__ out, long long nd4, long long n4) {
    long long i = (long long)blockIdx.x * 256 + threadIdx.x;
    if (i >= n4) return;
    const float* src = (i < nd4) ? (xd + i * 4) : (xq + (i - nd4) * 4);
    float4 v = *(const float4*)src;
    us4 o;
    o[0] = f2bf(v.x); o[1] = f2bf(v.y); o[2] = f2bf(v.z); o[3] = f2bf(v.w);
    *(us4*)(out + i * 4) = o;
}

// ---------------- CSR build (dual: data blocks then query blocks) ----------------

__global__ void count_deg_both(const int* __restrict__ d_dst, int* __restrict__ d_deg,
                               const int* __restrict__ q_dst, int* __restrict__ q_deg,
                               int dblocks) {
    int b = blockIdx.x;
    if (b < dblocks) {
        int e = b * 256 + threadIdx.x;
        if (e < ED) atomicAdd(&d_deg[d_dst[e]], 1);
    } else {
        int e = (b - dblocks) * 256 + threadIdx.x;
        if (e < EQ) atomicAdd(&q_deg[q_dst[e]], 1);
    }
}

__device__ __forceinline__ void scan1_body(const int* deg, int* rowptr, int* bsum,
                                           int n, int blk) {
    __shared__ int sh[256];
    const int t = threadIdx.x;
    const int i = blk * 256 + t;
    const int v = (i < n) ? deg[i] : 0;
    sh[t] = v;
    __syncthreads();
    for (int off = 1; off < 256; off <<= 1) {
        int x = (t >= off) ? sh[t - off] : 0;
        __syncthreads();
        sh[t] += x;
        __syncthreads();
    }
    if (i < n) rowptr[i] = sh[t] - v;
    if (t == 255) bsum[blk] = sh[255];
}

__global__ void scan_phase1_both(const int* __restrict__ d_deg, int* __restrict__ d_rowptr,
                                 int* __restrict__ d_bsum,
                                 const int* __restrict__ q_deg, int* __restrict__ q_rowptr,
                                 int* __restrict__ q_bsum, int dblocks) {
    int b = blockIdx.x;
    if (b < dblocks) scan1_body(d_deg, d_rowptr, d_bsum, ND, b);
    else             scan1_body(q_deg, q_rowptr, q_bsum, NQ, b - dblocks);
}

__device__ __forceinline__ void scan2_body(const int* bsum, int* boff, int* rowptr_n, int nb) {
    __shared__ int sh[256];
    const int t = threadIdx.x;
    const int v = (t < nb) ? bsum[t] : 0;
    sh[t] = v;
    __syncthreads();
    for (int off = 1; off < 256; off <<= 1) {
        int x = (t >= off) ? sh[t - off] : 0;
        __syncthreads();
        sh[t] += x;
        __syncthreads();
    }
    if (t < nb) boff[t] = sh[t] - v;
    if (t == 255) *rowptr_n = sh[255];
}

__global__ void scan_phase2_both(const int* __restrict__ d_bsum, int* __restrict__ d_boff,
                                 int* __restrict__ d_rowptr_n, int d_nb,
                                 const int* __restrict__ q_bsum, int* __restrict__ q_boff,
                                 int* __restrict__ q_rowptr_n, int q_nb) {
    if (blockIdx.x == 0) scan2_body(d_bsum, d_boff, d_rowptr_n, d_nb);
    else                 scan2_body(q_bsum, q_boff, q_rowptr_n, q_nb);
}

__global__ void scan_phase3_both(int* __restrict__ d_rowptr, const int* __restrict__ d_boff,
                                 int* __restrict__ d_cursor,
                                 int* __restrict__ q_rowptr, const int* __restrict__ q_boff,
                                 int* __restrict__ q_cursor, int dblocks) {
    int b = blockIdx.x;
    if (b < dblocks) {
        int i = b * 256 + threadIdx.x;
        if (i < ND) {
            int r = d_rowptr[i] + d_boff[b];
            d_rowptr[i] = r; d_cursor[i] = r;
        }
    } else {
        int i = (b - dblocks) * 256 + threadIdx.x;
        if (i < NQ) {
            int r = q_rowptr[i] + q_boff[b - dblocks];
            q_rowptr[i] = r; q_cursor[i] = r;
        }
    }
}

__global__ void fill_csr_both(const int* __restrict__ d_src, const int* __restrict__ d_dst,
                              int* __restrict__ d_cursor, int* __restrict__ d_csrsrc,
                              const int* __restrict__ q_src, const int* __restrict__ q_dst,
                              int* __restrict__ q_cursor, int* __restrict__ q_csrsrc,
                              int dblocks) {
    int b = blockIdx.x;
    if (b < dblocks) {
        int e = b * 256 + threadIdx.x;
        if (e < ED) {
            int p = atomicAdd(&d_cursor[d_dst[e]], 1);
            d_csrsrc[p] = d_src[e];
        }
    } else {
        int e = (b - dblocks) * 256 + threadIdx.x;
        if (e < EQ) {
            int p = atomicAdd(&q_cursor[q_dst[e]], 1);
            q_csrsrc[p] = q_src[e];
        }
    }
}

// ---------------- weight packing: all 8 matrices, one launch ----------------
// Wp layout: [ct(16)][kt(KT)][lane(64)][j(8)]; elem = W[kt*32+(l>>4)*8+j][ct*16+(l&15)]

struct PackDesc {
    const float* W[8];
    unsigned short* Wp[8];
    int KT[8];
    int start[9];
};

__global__ void pack_all(PackDesc pd) {
    int b = blockIdx.x;
    int m = 0;
    while (m < 7 && b >= pd.start[m + 1]) ++m;
    const int local = b - pd.start[m];
    const int KT = pd.KT[m];
    const int kt = local % KT;
    const int ct = local / KT;
    const float* W = pd.W[m];
    unsigned short* Wp = pd.Wp[m];
    const int l = threadIdx.x;  // 0..63
    const int row = kt * 32 + (l >> 4) * 8;
    const int col = ct * 16 + (l & 15);
    short8 v;
#pragma unroll
    for (int j = 0; j < 8; ++j) v[j] = (short)f2bf(W[(size_t)(row + j) * 256 + col]);
    *(short8*)(Wp + (((size_t)(ct * KT + kt)) * 64 + l) * 8) = v;
}

// ---------------- fused GIN conv ----------------
// out = [relu?]( relu( (x+agg(x)) @ W1 + b1 ) @ W2 + b2 );  optional pool colsum.
// Block = 64 rows x 256 cols, 4 waves. Dual: data blocks [0,ndb), query block ndb.

template <int KIN>
__global__ __launch_bounds__(256) void gin_conv_dual(
    const unsigned short* __restrict__ Xd, const int* __restrict__ rpd,
    const int* __restrict__ csd,
    const unsigned short* __restrict__ W1pd, const float* __restrict__ b1d,
    const unsigned short* __restrict__ W2pd, const float* __restrict__ b2d,
    unsigned short* __restrict__ Cd, float* __restrict__ poold, int ndb,
    const unsigned short* __restrict__ Xq, const int* __restrict__ rpq,
    const int* __restrict__ csq,
    const unsigned short* __restrict__ W1pq, const float* __restrict__ b1q,
    const unsigned short* __restrict__ W2pq, const float* __restrict__ b2q,
    unsigned short* __restrict__ Cq, float* __restrict__ poolq,
    int relu_out) {
    constexpr int KT1 = KIN / 32;
    constexpr int V = KIN / 64;              // feats per lane in gather
    __shared__ __align__(16) unsigned short lds[64 * 256];  // 32 KB, reused

    const unsigned short* X; const int* rowptr; const int* csr;
    const unsigned short* W1p; const float* b1; const unsigned short* W2p; const float* b2;
    unsigned short* C; float* pool; int row0, N;
    if ((int)blockIdx.x < ndb) {
        X = Xd; rowptr = rpd; csr = csd; W1p = W1pd; b1 = b1d; W2p = W2pd; b2 = b2d;
        C = Cd; pool = poold; row0 = blockIdx.x * 64; N = ND;
    } else {
        X = Xq; rowptr = rpq; csr = csq; W1p = W1pq; b1 = b1q; W2p = W2pq; b2 = b2q;
        C = Cq; pool = poolq; row0 = 0; N = NQ;
    }

    const int tid = threadIdx.x;
    const int lane = tid & 63;
    const int wv = tid >> 6;
    const int lrow = lane & 15;
    const int lk2 = (lane >> 4) * 8;

    // ---- stage: gather self+neighbors into lds (bf16, stride KIN, XOR swizzle) ----
    for (int i = 0; i < 16; ++i) {
        const int r = wv * 16 + i;
        const int gr = row0 + r;
        float acc[V];
#pragma unroll
        for (int u = 0; u < V; ++u) acc[u] = 0.f;
        if (gr < N) {
            {
                const unsigned short* p = X + (size_t)gr * KIN + lane * V;
                if constexpr (V == 4) {
                    us4 v = *(const us4*)p;
#pragma unroll
                    for (int u = 0; u < 4; ++u) acc[u] = bf2f(v[u]);
                } else {
                    us2 v = *(const us2*)p;
                    acc[0] = bf2f(v[0]); acc[1] = bf2f(v[1]);
                }
            }
            const int beg = rowptr[gr];
            const int end = rowptr[gr + 1];
            int j = beg;
            for (; j + 1 < end; j += 2) {
                const unsigned short* p0 = X + (size_t)csr[j] * KIN + lane * V;
                const unsigned short* p1 = X + (size_t)csr[j + 1] * KIN + lane * V;
                if constexpr (V == 4) {
                    us4 v0 = *(const us4*)p0;
                    us4 v1 = *(const us4*)p1;
#pragma unroll
                    for (int u = 0; u < 4; ++u) acc[u] += bf2f(v0[u]) + bf2f(v1[u]);
                } else {
                    us2 v0 = *(const us2*)p0;
                    us2 v1 = *(const us2*)p1;
                    acc[0] += bf2f(v0[0]) + bf2f(v1[0]);
                    acc[1] += bf2f(v0[1]) + bf2f(v1[1]);
                }
            }
            if (j < end) {
                const unsigned short* p0 = X + (size_t)csr[j] * KIN + lane * V;
                if constexpr (V == 4) {
                    us4 v0 = *(const us4*)p0;
#pragma unroll
                    for (int u = 0; u < 4; ++u) acc[u] += bf2f(v0[u]);
                } else {
                    us2 v0 = *(const us2*)p0;
                    acc[0] += bf2f(v0[0]); acc[1] += bf2f(v0[1]);
                }
            }
        }
        unsigned byte = (unsigned)((r * KIN + lane * V) * 2) ^ (unsigned)((r & 7) << 4);
        if constexpr (V == 4) {
            us4 w;
#pragma unroll
            for (int u = 0; u < 4; ++u) w[u] = f2bf(acc[u]);
            *(us4*)((char*)lds + byte) = w;
        } else {
            us2 w; w[0] = f2bf(acc[0]); w[1] = f2bf(acc[1]);
            *(us2*)((char*)lds + byte) = w;
        }
    }
    __syncthreads();

    // ---- pass 1: T1 = relu(A @ W1 + b1) ----
    f32x4 acc1[4][4];
#pragma unroll
    for (int fm = 0; fm < 4; ++fm)
#pragma unroll
        for (int fn = 0; fn < 4; ++fn) acc1[fm][fn] = (f32x4)(0.f);

    const unsigned short* W1Base = W1p + ((size_t)(wv * 4) * KT1 * 64 + lane) * 8;
    for (int kt = 0; kt < KT1; ++kt) {
        short8 a[4], bf[4];
#pragma unroll
        for (int fm = 0; fm < 4; ++fm) {
            const int r = fm * 16 + lrow;
            unsigned byte = (unsigned)((r * KIN + kt * 32 + lk2) * 2) ^ (unsigned)((r & 7) << 4);
            a[fm] = *(const short8*)((const char*)lds + byte);
        }
#pragma unroll
        for (int fn = 0; fn < 4; ++fn)
            bf[fn] = *(const short8*)(W1Base + ((size_t)fn * KT1 + kt) * 64 * 8);
#pragma unroll
        for (int fm = 0; fm < 4; ++fm)
#pragma unroll
            for (int fn = 0; fn < 4; ++fn)
                acc1[fm][fn] = __builtin_amdgcn_mfma_f32_16x16x32_bf16(
                    a[fm], bf[fn], acc1[fm][fn], 0, 0, 0);
    }
    __syncthreads();  // all pass-1 LDS reads done before T1 overwrites

    // ---- T1 tile (bias + relu, bf16) into lds, stride 256, same swizzle ----
#pragma unroll
    for (int fn = 0; fn < 4; ++fn) {
        const int col = wv * 64 + fn * 16 + lrow;
        const float bv = b1[col];
#pragma unroll
        for (int fm = 0; fm < 4; ++fm) {
            const int rbase = fm * 16 + (lane >> 4) * 4;
#pragma unroll
            for (int r = 0; r < 4; ++r) {
                const int row = rbase + r;
                const float v = fmaxf(acc1[fm][fn][r] + bv, 0.f);
                unsigned byte = (unsigned)((row * 256 + col) * 2) ^ (unsigned)((row & 7) << 4);
                *(unsigned short*)((char*)lds + byte) = f2bf(v);
            }
        }
    }
    __syncthreads();

    // ---- pass 2: out = T1 @ W2 + b2 ----
    f32x4 acc2[4][4];
#pragma unroll
    for (int fm = 0; fm < 4; ++fm)
#pragma unroll
        for (int fn = 0; fn < 4; ++fn) acc2[fm][fn] = (f32x4)(0.f);

    const unsigned short* W2Base = W2p + ((size_t)(wv * 4) * 8 * 64 + lane) * 8;
    for (int kt = 0; kt < 8; ++kt) {
        short8 a[4], bf[4];
#pragma unroll
        for (int fm = 0; fm < 4; ++fm) {
            const int r = fm * 16 + lrow;
            unsigned byte = (unsigned)((r * 256 + kt * 32 + lk2) * 2) ^ (unsigned)((r & 7) << 4);
            a[fm] = *(const short8*)((const char*)lds + byte);
        }
#pragma unroll
        for (int fn = 0; fn < 4; ++fn)
            bf[fn] = *(const short8*)(W2Base + ((size_t)fn * 8 + kt) * 64 * 8);
#pragma unroll
        for (int fm = 0; fm < 4; ++fm)
#pragma unroll
            for (int fn = 0; fn < 4; ++fn)
                acc2[fm][fn] = __builtin_amdgcn_mfma_f32_16x16x32_bf16(
                    a[fm], bf[fn], acc2[fm][fn], 0, 0, 0);
    }

    // ---- epilogue: bias2 (+relu_out), store bf16 C / pool colsum ----
#pragma unroll
    for (int fn = 0; fn < 4; ++fn) {
        const int col = wv * 64 + fn * 16 + lrow;
        const float bv = b2[col];
        float ps = 0.f;
#pragma unroll
        for (int fm = 0; fm < 4; ++fm) {
            const int rbase = row0 + fm * 16 + (lane >> 4) * 4;
#pragma unroll
            for (int r = 0; r < 4; ++r) {
                const int row = rbase + r;
                if (row < N) {
                    float v = acc2[fm][fn][r] + bv;
                    if (relu_out) v = fmaxf(v, 0.f);
                    if (C) C[(size_t)row * 256 + col] = f2bf(v);
                    ps += v;
                }
            }
        }
        if (pool) {
            ps += __shfl_xor(ps, 16);
            ps += __shfl_xor(ps, 32);
            if ((lane >> 4) == 0) atomicAdd(&pool[col], ps);
        }
    }
}

// ---------------- head ----------------

__global__ void mlp_head(const float* __restrict__ pooled,
                         const float* __restrict__ lW1, const float* __restrict__ lb1,
                         const float* __restrict__ lW2, const float* __restrict__ lb2,
                         const float* __restrict__ lW3, const float* __restrict__ lb3,
                         float* __restrict__ out) {
    __shared__ float h0[512];
    __shared__ float h1[256];
    __shared__ float h2[128];
    const int t = threadIdx.x;  // 256 threads
    h0[t] = pooled[t];
    h0[t + 256] = pooled[t + 256];
    __syncthreads();

    float acc = lb1[t];
    for (int k = 0; k < 512; ++k) acc += h0[k] * lW1[k * 256 + t];
    h1[t] = fmaxf(acc, 0.f);
    __syncthreads();

    if (t < 128) {
        float a = lb2[t];
        for (int k = 0; k < 256; ++k) a += h1[k] * lW2[k * 128 + t];
        h2[t] = fmaxf(a, 0.f);
    }
    __syncthreads();

    if (t < 8) {
        float a = lb3[t];
        for (int k = 0; k < 128; ++k) a += h2[k] * lW3[k * 8 + t];
        out[t] = fmaxf(a, 0.f);
    }
}

// ---------------------------------------------------------------------------

extern "C" void kernel_launch(void* const* d_in, const int* in_sizes, int n_in,
                              void* d_out, int out_size, void* d_ws, size_t ws_size,
                              hipStream_t stream) {
    const float* q_x  = (const float*)d_in[0];
    const float* d_x  = (const float*)d_in[1];
    const int*   q_el = (const int*)d_in[2];
    const int*   d_el = (const int*)d_in[3];
    const float* qW1 = (const float*)d_in[4];  const float* qb1 = (const float*)d_in[5];
    const float* qW2 = (const float*)d_in[6];  const float* qb2 = (const float*)d_in[7];
    const float* qW3 = (const float*)d_in[8];  const float* qb3 = (const float*)d_in[9];
    const float* qW4 = (const float*)d_in[10]; const float* qb4 = (const float*)d_in[11];
    const float* dW1 = (const float*)d_in[12]; const float* db1 = (const float*)d_in[13];
    const float* dW2 = (const float*)d_in[14]; const float* db2 = (const float*)d_in[15];
    const float* dW3 = (const float*)d_in[16]; const float* db3 = (const float*)d_in[17];
    const float* dW4 = (const float*)d_in[18]; const float* db4 = (const float*)d_in[19];
    const float* lW1 = (const float*)d_in[20]; const float* lb1 = (const float*)d_in[21];
    const float* lW2 = (const float*)d_in[22]; const float* lb2 = (const float*)d_in[23];
    const float* lW3 = (const float*)d_in[24]; const float* lb3 = (const float*)d_in[25];
    (void)in_sizes; (void)n_in; (void)out_size; (void)ws_size;

    const int* q_src = q_el;  const int* q_dst = q_el + EQ;
    const int* d_src = d_el;  const int* d_dst = d_el + ED;

    // ---- workspace layout ----
    char* wsb = (char*)d_ws;
    size_t off = 0;
    auto alloc = [&](size_t bytes) { void* p = wsb + off; off += (bytes + 255) & ~(size_t)255; return p; };

    unsigned short* bxd = (unsigned short*)alloc((size_t)ND * FDIM * 2);  // bf16 d_x
    unsigned short* bxq = (unsigned short*)alloc((size_t)NQ * FDIM * 2);  // adjacent
    unsigned short* hd  = (unsigned short*)alloc((size_t)ND * HDIM * 2);  // conv1 out (data)
    unsigned short* hq  = (unsigned short*)alloc((size_t)NQ * HDIM * 2);
    float* pooled = (float*)alloc(512 * 4);
    int* d_deg    = (int*)alloc((size_t)ND * 4);
    int* q_deg    = (int*)alloc((size_t)NQ * 4);   // adjacent to d_deg (one memset)
    int* d_rowptr = (int*)alloc((size_t)(ND + 1) * 4);
    int* d_cursor = (int*)alloc((size_t)ND * 4);
    int* d_csrsrc = (int*)alloc((size_t)ED * 4);
    int* d_bsum   = (int*)alloc(256 * 4);
    int* d_boff   = (int*)alloc(256 * 4);
    int* q_rowptr = (int*)alloc((size_t)(NQ + 1) * 4);
    int* q_cursor = (int*)alloc((size_t)NQ * 4);
    int* q_csrsrc = (int*)alloc((size_t)EQ * 4);
    int* q_bsum   = (int*)alloc(256 * 4);
    int* q_boff   = (int*)alloc(256 * 4);
    unsigned short* pdW1 = (unsigned short*)alloc((size_t)FDIM * 256 * 2);
    unsigned short* pdW2 = (unsigned short*)alloc((size_t)HDIM * 256 * 2);
    unsigned short* pdW3 = (unsigned short*)alloc((size_t)HDIM * 256 * 2);
    unsigned short* pdW4 = (unsigned short*)alloc((size_t)HDIM * 256 * 2);
    unsigned short* pqW1 = (unsigned short*)alloc((size_t)FDIM * 256 * 2);
    unsigned short* pqW2 = (unsigned short*)alloc((size_t)HDIM * 256 * 2);
    unsigned short* pqW3 = (unsigned short*)alloc((size_t)HDIM * 256 * 2);
    unsigned short* pqW4 = (unsigned short*)alloc((size_t)HDIM * 256 * 2);

    hipMemsetAsync(pooled, 0, 512 * 4, stream);
    hipMemsetAsync(d_deg, 0, (char*)(q_deg + NQ) - (char*)d_deg, stream);

    // ---- input conversion ----
    {
        long long nd4 = (long long)ND * FDIM / 4;
        long long n4 = nd4 + (long long)NQ * FDIM / 4;
        cvt_to_bf16<<<(int)((n4 + 255) / 256), 256, 0, stream>>>(d_x, q_x, bxd, nd4, n4);
    }

    // ---- weight packing (one launch) ----
    {
        PackDesc pd;
        const float* Ws[8] = {dW1, dW2, dW3, dW4, qW1, qW2, qW3, qW4};
        unsigned short* Wps[8] = {pdW1, pdW2, pdW3, pdW4, pqW1, pqW2, pqW3, pqW4};
        int kts[8] = {4, 8, 8, 8, 4, 8, 8, 8};
        int s = 0;
        for (int i = 0; i < 8; ++i) {
            pd.W[i] = Ws[i]; pd.Wp[i] = Wps[i]; pd.KT[i] = kts[i];
            pd.start[i] = s; s += 16 * kts[i];
        }
        pd.start[8] = s;
        pack_all<<<s, 64, 0, stream>>>(pd);
    }

    // ---- CSR build ----
    const int d_eb = (ED + 255) / 256;
    const int q_eb = (EQ + 255) / 256;
    const int d_nb = (ND + 255) / 256;
    const int q_nb = (NQ + 255) / 256;
    count_deg_both<<<d_eb + q_eb, 256, 0, stream>>>(d_dst, d_deg, q_dst, q_deg, d_eb);
    scan_phase1_both<<<d_nb + q_nb, 256, 0, stream>>>(d_deg, d_rowptr, d_bsum,
                                                      q_deg, q_rowptr, q_bsum, d_nb);
    scan_phase2_both<<<2, 256, 0, stream>>>(d_bsum, d_boff, d_rowptr + ND, d_nb,
                                            q_bsum, q_boff, q_rowptr + NQ, q_nb);
    scan_phase3_both<<<d_nb + q_nb, 256, 0, stream>>>(d_rowptr, d_boff, d_cursor,
                                                      q_rowptr, q_boff, q_cursor, d_nb);
    fill_csr_both<<<d_eb + q_eb, 256, 0, stream>>>(d_src, d_dst, d_cursor, d_csrsrc,
                                                   q_src, q_dst, q_cursor, q_csrsrc, d_eb);

    // ---- fused convs ----
    const int ndb = (ND + 63) / 64;  // 782

    // conv1: h = relu(MLP1(x + agg(x)))
    gin_conv_dual<FDIM><<<ndb + 1, 256, 0, stream>>>(
        bxd, d_rowptr, d_csrsrc, pdW1, db1, pdW2, db2, hd, nullptr, ndb,
        bxq, q_rowptr, q_csrsrc, pqW1, qb1, pqW2, qb2, hq, nullptr, 1);

    // conv2: y = MLP2(h + agg(h)); pool colsum, no store
    gin_conv_dual<HDIM><<<ndb + 1, 256, 0, stream>>>(
        hd, d_rowptr, d_csrsrc, pdW3, db3, pdW4, db4, nullptr, pooled + 256, ndb,
        hq, q_rowptr, q_csrsrc, pqW3, qb3, pqW4, qb4, nullptr, pooled, 0);

    // ---- head ----
    mlp_head<<<1, 256, 0, stream>>>(pooled, lW1, lb1, lW2, lb2, lW3, lb3, (float*)d_out);
}

// Round 7
// 260.950 us; speedup vs baseline: 1.8320x; 1.8320x over previous
//
#include <hip/hip_runtime.h>
#include <hip/hip_bf16.h>

// ---------------------------------------------------------------------------
// BasicCountNet round 7:
//   - standalone high-occupancy CSR gather agg (round-5 win restored; round-6
//     lesson: gather fused into GEMM blocks is chain-latency-bound)
//   - fused MLP kernel per conv: stage A (linear bf16), MFMA pass1 (W1+b1,
//     ReLU), T1 in LDS, MFMA pass2 (W2+b2), store/pool. Saves one dispatch +
//     50 MB T1 round-trip per conv; conv2 MLP is pool-only (no C store).
//   - 13 dispatches total.
// ---------------------------------------------------------------------------

#define NQ 64
#define EQ 512
#define ND 50000
#define ED 600000
#define FDIM 128
#define HDIM 256

typedef __attribute__((ext_vector_type(8))) short short8;
typedef __attribute__((ext_vector_type(4))) float f32x4;
typedef __attribute__((ext_vector_type(4))) unsigned short us4;
typedef __attribute__((ext_vector_type(2))) unsigned short us2;

__device__ __forceinline__ unsigned short f2bf(float f) {
    union { float f; unsigned u; } v; v.f = f;
    unsigned r = v.u + 0x7FFF + ((v.u >> 16) & 1);   // RNE
    return (unsigned short)(r >> 16);
}
__device__ __forceinline__ float bf2f(unsigned short u) {
    union { unsigned u; float f; } v; v.u = ((unsigned)u) << 16;
    return v.f;
}

// ---------------- fp32 -> bf16 conversion (both inputs, adjacent dests) ----------------

__global__ void cvt_to_bf16(const float* __restrict__ xd, const float* __restrict__ xq,
                            unsigned short* __restrict__ out, long long nd4, long long n4) {
    long long i = (long long)blockIdx.x * 256 + threadIdx.x;
    if (i >= n4) return;
    const float* src = (i < nd4) ? (xd + i * 4) : (xq + (i - nd4) * 4);
    float4 v = *(const float4*)src;
    us4 o;
    o[0] = f2bf(v.x); o[1] = f2bf(v.y); o[2] = f2bf(v.z); o[3] = f2bf(v.w);
    *(us4*)(out + i * 4) = o;
}

// ---------------- CSR build (dual: data blocks then query blocks) ----------------

__global__ void count_deg_both(const int* __restrict__ d_dst, int* __restrict__ d_deg,
                               const int* __restrict__ q_dst, int* __restrict__ q_deg,
                               int dblocks) {
    int b = blockIdx.x;
    if (b < dblocks) {
        int e = b * 256 + threadIdx.x;
        if (e < ED) atomicAdd(&d_deg[d_dst[e]], 1);
    } else {
        int e = (b - dblocks) * 256 + threadIdx.x;
        if (e < EQ) atomicAdd(&q_deg[q_dst[e]], 1);
    }
}

__device__ __forceinline__ void scan1_body(const int* deg, int* rowptr, int* bsum,
                                           int n, int blk) {
    __shared__ int sh[256];
    const int t = threadIdx.x;
    const int i = blk * 256 + t;
    const int v = (i < n) ? deg[i] : 0;
    sh[t] = v;
    __syncthreads();
    for (int off = 1; off < 256; off <<= 1) {
        int x = (t >= off) ? sh[t - off] : 0;
        __syncthreads();
        sh[t] += x;
        __syncthreads();
    }
    if (i < n) rowptr[i] = sh[t] - v;
    if (t == 255) bsum[blk] = sh[255];
}

__global__ void scan_phase1_both(const int* __restrict__ d_deg, int* __restrict__ d_rowptr,
                                 int* __restrict__ d_bsum,
                                 const int* __restrict__ q_deg, int* __restrict__ q_rowptr,
                                 int* __restrict__ q_bsum, int dblocks) {
    int b = blockIdx.x;
    if (b < dblocks) scan1_body(d_deg, d_rowptr, d_bsum, ND, b);
    else             scan1_body(q_deg, q_rowptr, q_bsum, NQ, b - dblocks);
}

__device__ __forceinline__ void scan2_body(const int* bsum, int* boff, int* rowptr_n, int nb) {
    __shared__ int sh[256];
    const int t = threadIdx.x;
    const int v = (t < nb) ? bsum[t] : 0;
    sh[t] = v;
    __syncthreads();
    for (int off = 1; off < 256; off <<= 1) {
        int x = (t >= off) ? sh[t - off] : 0;
        __syncthreads();
        sh[t] += x;
        __syncthreads();
    }
    if (t < nb) boff[t] = sh[t] - v;
    if (t == 255) *rowptr_n = sh[255];
}

__global__ void scan_phase2_both(const int* __restrict__ d_bsum, int* __restrict__ d_boff,
                                 int* __restrict__ d_rowptr_n, int d_nb,
                                 const int* __restrict__ q_bsum, int* __restrict__ q_boff,
                                 int* __restrict__ q_rowptr_n, int q_nb) {
    if (blockIdx.x == 0) scan2_body(d_bsum, d_boff, d_rowptr_n, d_nb);
    else                 scan2_body(q_bsum, q_boff, q_rowptr_n, q_nb);
}

__global__ void scan_phase3_both(int* __restrict__ d_rowptr, const int* __restrict__ d_boff,
                                 int* __restrict__ d_cursor,
                                 int* __restrict__ q_rowptr, const int* __restrict__ q_boff,
                                 int* __restrict__ q_cursor, int dblocks) {
    int b = blockIdx.x;
    if (b < dblocks) {
        int i = b * 256 + threadIdx.x;
        if (i < ND) {
            int r = d_rowptr[i] + d_boff[b];
            d_rowptr[i] = r; d_cursor[i] = r;
        }
    } else {
        int i = (b - dblocks) * 256 + threadIdx.x;
        if (i < NQ) {
            int r = q_rowptr[i] + q_boff[b - dblocks];
            q_rowptr[i] = r; q_cursor[i] = r;
        }
    }
}

__global__ void fill_csr_both(const int* __restrict__ d_src, const int* __restrict__ d_dst,
                              int* __restrict__ d_cursor, int* __restrict__ d_csrsrc,
                              const int* __restrict__ q_src, const int* __restrict__ q_dst,
                              int* __restrict__ q_cursor, int* __restrict__ q_csrsrc,
                              int dblocks) {
    int b = blockIdx.x;
    if (b < dblocks) {
        int e = b * 256 + threadIdx.x;
        if (e < ED) {
            int p = atomicAdd(&d_cursor[d_dst[e]], 1);
            d_csrsrc[p] = d_src[e];
        }
    } else {
        int e = (b - dblocks) * 256 + threadIdx.x;
        if (e < EQ) {
            int p = atomicAdd(&q_cursor[q_dst[e]], 1);
            q_csrsrc[p] = q_src[e];
        }
    }
}

// ---------------- aggregation (bf16 in / bf16 out, fp32 accumulate) ----------------
// out[n] = x[n] + sum_{j in N(n)} x[j];  one wave per node; dual data+query

template <int F>
__global__ void gin_agg_dual(const unsigned short* __restrict__ xd, const int* __restrict__ rpd,
                             const int* __restrict__ csd, unsigned short* __restrict__ od,
                             const unsigned short* __restrict__ xq, const int* __restrict__ rpq,
                             const int* __restrict__ csq, unsigned short* __restrict__ oq) {
    constexpr int V = F / 64;  // 4 (F=256) or 2 (F=128)
    const unsigned short* x; const int* rowptr; const int* csr; unsigned short* out; int node;
    if ((int)blockIdx.x < ND) { x = xd; rowptr = rpd; csr = csd; out = od; node = blockIdx.x; }
    else { x = xq; rowptr = rpq; csr = csq; out = oq; node = blockIdx.x - ND; }

    const int t = threadIdx.x;  // 0..63
    const int beg = rowptr[node];
    const int end = rowptr[node + 1];

    float acc[V];
    {
        const unsigned short* p = x + (size_t)node * F + t * V;
        if constexpr (V == 4) {
            us4 v = *(const us4*)p;
#pragma unroll
            for (int i = 0; i < 4; ++i) acc[i] = bf2f(v[i]);
        } else {
            us2 v = *(const us2*)p;
            acc[0] = bf2f(v[0]); acc[1] = bf2f(v[1]);
        }
    }
    int j = beg;
    for (; j + 1 < end; j += 2) {
        const unsigned short* p0 = x + (size_t)csr[j] * F + t * V;
        const unsigned short* p1 = x + (size_t)csr[j + 1] * F + t * V;
        if constexpr (V == 4) {
            us4 v0 = *(const us4*)p0;
            us4 v1 = *(const us4*)p1;
#pragma unroll
            for (int i = 0; i < 4; ++i) acc[i] += bf2f(v0[i]) + bf2f(v1[i]);
        } else {
            us2 v0 = *(const us2*)p0;
            us2 v1 = *(const us2*)p1;
            acc[0] += bf2f(v0[0]) + bf2f(v1[0]);
            acc[1] += bf2f(v0[1]) + bf2f(v1[1]);
        }
    }
    if (j < end) {
        const unsigned short* p0 = x + (size_t)csr[j] * F + t * V;
        if constexpr (V == 4) {
            us4 v0 = *(const us4*)p0;
#pragma unroll
            for (int i = 0; i < 4; ++i) acc[i] += bf2f(v0[i]);
        } else {
            us2 v0 = *(const us2*)p0;
            acc[0] += bf2f(v0[0]); acc[1] += bf2f(v0[1]);
        }
    }
    unsigned short* po = out + (size_t)node * F + t * V;
    if constexpr (V == 4) {
        us4 r;
#pragma unroll
        for (int i = 0; i < 4; ++i) r[i] = f2bf(acc[i]);
        *(us4*)po = r;
    } else {
        us2 r; r[0] = f2bf(acc[0]); r[1] = f2bf(acc[1]);
        *(us2*)po = r;
    }
}

// ---------------- weight packing: all 8 matrices, one launch ----------------
// Wp layout: [ct(16)][kt(KT)][lane(64)][j(8)]; elem = W[kt*32+(l>>4)*8+j][ct*16+(l&15)]

struct PackDesc {
    const float* W[8];
    unsigned short* Wp[8];
    int KT[8];
    int start[9];
};

__global__ void pack_all(PackDesc pd) {
    int b = blockIdx.x;
    int m = 0;
    while (m < 7 && b >= pd.start[m + 1]) ++m;
    const int local = b - pd.start[m];
    const int KT = pd.KT[m];
    const int kt = local % KT;
    const int ct = local / KT;
    const float* W = pd.W[m];
    unsigned short* Wp = pd.Wp[m];
    const int l = threadIdx.x;  // 0..63
    const int row = kt * 32 + (l >> 4) * 8;
    const int col = ct * 16 + (l & 15);
    short8 v;
#pragma unroll
    for (int j = 0; j < 8; ++j) v[j] = (short)f2bf(W[(size_t)(row + j) * 256 + col]);
    *(short8*)(Wp + (((size_t)(ct * KT + kt)) * 64 + l) * 8) = v;
}

// ---------------- fused MLP: out = [relu?]( relu(A @ W1 + b1) @ W2 + b2 ) ----------------
// Block = 64 rows x 256 cols, 4 waves. Dual: data blocks [0,ndb), query block ndb.
// A is bf16 [N,KIN]; T1 (64x256) stays in LDS; optional pool colsum; C optional.

template <int KIN>
__global__ __launch_bounds__(256) void mlp_dual(
    const unsigned short* __restrict__ Ad,
    const unsigned short* __restrict__ W1pd, const float* __restrict__ b1d,
    const unsigned short* __restrict__ W2pd, const float* __restrict__ b2d,
    unsigned short* __restrict__ Cd, float* __restrict__ poold, int ndb,
    const unsigned short* __restrict__ Aq,
    const unsigned short* __restrict__ W1pq, const float* __restrict__ b1q,
    const unsigned short* __restrict__ W2pq, const float* __restrict__ b2q,
    unsigned short* __restrict__ Cq, float* __restrict__ poolq,
    int relu_out) {
    constexpr int KT1 = KIN / 32;
    __shared__ __align__(16) unsigned short lds[64 * 256];  // 32 KB, A then T1

    const unsigned short* A; const unsigned short* W1p; const float* b1;
    const unsigned short* W2p; const float* b2;
    unsigned short* C; float* pool; int row0, N;
    if ((int)blockIdx.x < ndb) {
        A = Ad; W1p = W1pd; b1 = b1d; W2p = W2pd; b2 = b2d;
        C = Cd; pool = poold; row0 = blockIdx.x * 64; N = ND;
    } else {
        A = Aq; W1p = W1pq; b1 = b1q; W2p = W2pq; b2 = b2q;
        C = Cq; pool = poolq; row0 = 0; N = NQ;
    }

    const int tid = threadIdx.x;
    const int lane = tid & 63;
    const int wv = tid >> 6;
    const int lrow = lane & 15;
    const int lk2 = (lane >> 4) * 8;
    const int nrows = (N - row0 < 64) ? (N - row0) : 64;

    // ---- stage A: linear coalesced bf16 loads, swizzled 16B LDS writes ----
    for (int idx = tid; idx < nrows * (KIN / 8); idx += 256) {
        const int r = idx / (KIN / 8);
        const int k8 = (idx % (KIN / 8)) * 8;
        short8 v = *(const short8*)(A + (size_t)(row0 + r) * KIN + k8);
        unsigned byte = (unsigned)((r * KIN + k8) * 2) ^ (unsigned)((r & 7) << 4);
        *(short8*)((char*)lds + byte) = v;
    }
    __syncthreads();

    // ---- pass 1: T1 = relu(A @ W1 + b1) ----
    f32x4 acc1[4][4];
#pragma unroll
    for (int fm = 0; fm < 4; ++fm)
#pragma unroll
        for (int fn = 0; fn < 4; ++fn) acc1[fm][fn] = (f32x4)(0.f);

    const unsigned short* W1Base = W1p + ((size_t)(wv * 4) * KT1 * 64 + lane) * 8;
    for (int kt = 0; kt < KT1; ++kt) {
        short8 a[4], bf[4];
#pragma unroll
        for (int fm = 0; fm < 4; ++fm) {
            const int r = fm * 16 + lrow;
            unsigned byte = (unsigned)((r * KIN + kt * 32 + lk2) * 2) ^ (unsigned)((r & 7) << 4);
            a[fm] = *(const short8*)((const char*)lds + byte);
        }
#pragma unroll
        for (int fn = 0; fn < 4; ++fn)
            bf[fn] = *(const short8*)(W1Base + ((size_t)fn * KT1 + kt) * 64 * 8);
#pragma unroll
        for (int fm = 0; fm < 4; ++fm)
#pragma unroll
            for (int fn = 0; fn < 4; ++fn)
                acc1[fm][fn] = __builtin_amdgcn_mfma_f32_16x16x32_bf16(
                    a[fm], bf[fn], acc1[fm][fn], 0, 0, 0);
    }
    __syncthreads();  // all pass-1 LDS reads done before T1 overwrites

    // ---- T1 tile (bias + relu, bf16) into lds, stride 256, same swizzle ----
#pragma unroll
    for (int fn = 0; fn < 4; ++fn) {
        const int col = wv * 64 + fn * 16 + lrow;
        const float bv = b1[col];
#pragma unroll
        for (int fm = 0; fm < 4; ++fm) {
            const int rbase = fm * 16 + (lane >> 4) * 4;
#pragma unroll
            for (int r = 0; r < 4; ++r) {
                const int row = rbase + r;
                const float v = fmaxf(acc1[fm][fn][r] + bv, 0.f);
                unsigned byte = (unsigned)((row * 256 + col) * 2) ^ (unsigned)((row & 7) << 4);
                *(unsigned short*)((char*)lds + byte) = f2bf(v);
            }
        }
    }
    __syncthreads();

    // ---- pass 2: out = T1 @ W2 + b2 ----
    f32x4 acc2[4][4];
#pragma unroll
    for (int fm = 0; fm < 4; ++fm)
#pragma unroll
        for (int fn = 0; fn < 4; ++fn) acc2[fm][fn] = (f32x4)(0.f);

    const unsigned short* W2Base = W2p + ((size_t)(wv * 4) * 8 * 64 + lane) * 8;
    for (int kt = 0; kt < 8; ++kt) {
        short8 a[4], bf[4];
#pragma unroll
        for (int fm = 0; fm < 4; ++fm) {
            const int r = fm * 16 + lrow;
            unsigned byte = (unsigned)((r * 256 + kt * 32 + lk2) * 2) ^ (unsigned)((r & 7) << 4);
            a[fm] = *(const short8*)((const char*)lds + byte);
        }
#pragma unroll
        for (int fn = 0; fn < 4; ++fn)
            bf[fn] = *(const short8*)(W2Base + ((size_t)fn * 8 + kt) * 64 * 8);
#pragma unroll
        for (int fm = 0; fm < 4; ++fm)
#pragma unroll
            for (int fn = 0; fn < 4; ++fn)
                acc2[fm][fn] = __builtin_amdgcn_mfma_f32_16x16x32_bf16(
                    a[fm], bf[fn], acc2[fm][fn], 0, 0, 0);
    }

    // ---- epilogue: bias2 (+relu_out), store bf16 C / pool colsum ----
#pragma unroll
    for (int fn = 0; fn < 4; ++fn) {
        const int col = wv * 64 + fn * 16 + lrow;
        const float bv = b2[col];
        float ps = 0.f;
#pragma unroll
        for (int fm = 0; fm < 4; ++fm) {
            const int rbase = row0 + fm * 16 + (lane >> 4) * 4;
#pragma unroll
            for (int r = 0; r < 4; ++r) {
                const int row = rbase + r;
                if (row < N) {
                    float v = acc2[fm][fn][r] + bv;
                    if (relu_out) v = fmaxf(v, 0.f);
                    if (C) C[(size_t)row * 256 + col] = f2bf(v);
                    ps += v;
                }
            }
        }
        if (pool) {
            ps += __shfl_xor(ps, 16);
            ps += __shfl_xor(ps, 32);
            if ((lane >> 4) == 0) atomicAdd(&pool[col], ps);
        }
    }
}

// ---------------- head ----------------

__global__ void mlp_head(const float* __restrict__ pooled,
                         const float* __restrict__ lW1, const float* __restrict__ lb1,
                         const float* __restrict__ lW2, const float* __restrict__ lb2,
                         const float* __restrict__ lW3, const float* __restrict__ lb3,
                         float* __restrict__ out) {
    __shared__ float h0[512];
    __shared__ float h1[256];
    __shared__ float h2[128];
    const int t = threadIdx.x;  // 256 threads
    h0[t] = pooled[t];
    h0[t + 256] = pooled[t + 256];
    __syncthreads();

    float acc = lb1[t];
    for (int k = 0; k < 512; ++k) acc += h0[k] * lW1[k * 256 + t];
    h1[t] = fmaxf(acc, 0.f);
    __syncthreads();

    if (t < 128) {
        float a = lb2[t];
        for (int k = 0; k < 256; ++k) a += h1[k] * lW2[k * 128 + t];
        h2[t] = fmaxf(a, 0.f);
    }
    __syncthreads();

    if (t < 8) {
        float a = lb3[t];
        for (int k = 0; k < 128; ++k) a += h2[k] * lW3[k * 8 + t];
        out[t] = fmaxf(a, 0.f);
    }
}

// ---------------------------------------------------------------------------

extern "C" void kernel_launch(void* const* d_in, const int* in_sizes, int n_in,
                              void* d_out, int out_size, void* d_ws, size_t ws_size,
                              hipStream_t stream) {
    const float* q_x  = (const float*)d_in[0];
    const float* d_x  = (const float*)d_in[1];
    const int*   q_el = (const int*)d_in[2];
    const int*   d_el = (const int*)d_in[3];
    const float* qW1 = (const float*)d_in[4];  const float* qb1 = (const float*)d_in[5];
    const float* qW2 = (const float*)d_in[6];  const float* qb2 = (const float*)d_in[7];
    const float* qW3 = (const float*)d_in[8];  const float* qb3 = (const float*)d_in[9];
    const float* qW4 = (const float*)d_in[10]; const float* qb4 = (const float*)d_in[11];
    const float* dW1 = (const float*)d_in[12]; const float* db1 = (const float*)d_in[13];
    const float* dW2 = (const float*)d_in[14]; const float* db2 = (const float*)d_in[15];
    const float* dW3 = (const float*)d_in[16]; const float* db3 = (const float*)d_in[17];
    const float* dW4 = (const float*)d_in[18]; const float* db4 = (const float*)d_in[19];
    const float* lW1 = (const float*)d_in[20]; const float* lb1 = (const float*)d_in[21];
    const float* lW2 = (const float*)d_in[22]; const float* lb2 = (const float*)d_in[23];
    const float* lW3 = (const float*)d_in[24]; const float* lb3 = (const float*)d_in[25];
    (void)in_sizes; (void)n_in; (void)out_size; (void)ws_size;

    const int* q_src = q_el;  const int* q_dst = q_el + EQ;
    const int* d_src = d_el;  const int* d_dst = d_el + ED;

    // ---- workspace layout ----
    char* wsb = (char*)d_ws;
    size_t off = 0;
    auto alloc = [&](size_t bytes) { void* p = wsb + off; off += (bytes + 255) & ~(size_t)255; return p; };

    unsigned short* bxd = (unsigned short*)alloc((size_t)ND * FDIM * 2);  // bf16 d_x
    unsigned short* bxq = (unsigned short*)alloc((size_t)NQ * FDIM * 2);  // adjacent
    unsigned short* dag = (unsigned short*)alloc((size_t)ND * FDIM * 2);  // agg1 out (data)
    unsigned short* qag = (unsigned short*)alloc((size_t)NQ * FDIM * 2);
    unsigned short* hd  = (unsigned short*)alloc((size_t)ND * HDIM * 2);  // conv1 out (data)
    unsigned short* hq  = (unsigned short*)alloc((size_t)NQ * HDIM * 2);
    unsigned short* had = (unsigned short*)alloc((size_t)ND * HDIM * 2);  // agg2 out (data)
    unsigned short* haq = (unsigned short*)alloc((size_t)NQ * HDIM * 2);
    float* pooled = (float*)alloc(512 * 4);
    int* d_deg    = (int*)alloc((size_t)ND * 4);
    int* q_deg    = (int*)alloc((size_t)NQ * 4);   // adjacent to d_deg (one memset)
    int* d_rowptr = (int*)alloc((size_t)(ND + 1) * 4);
    int* d_cursor = (int*)alloc((size_t)ND * 4);
    int* d_csrsrc = (int*)alloc((size_t)ED * 4);
    int* d_bsum   = (int*)alloc(256 * 4);
    int* d_boff   = (int*)alloc(256 * 4);
    int* q_rowptr = (int*)alloc((size_t)(NQ + 1) * 4);
    int* q_cursor = (int*)alloc((size_t)NQ * 4);
    int* q_csrsrc = (int*)alloc((size_t)EQ * 4);
    int* q_bsum   = (int*)alloc(256 * 4);
    int* q_boff   = (int*)alloc(256 * 4);
    unsigned short* pdW1 = (unsigned short*)alloc((size_t)FDIM * 256 * 2);
    unsigned short* pdW2 = (unsigned short*)alloc((size_t)HDIM * 256 * 2);
    unsigned short* pdW3 = (unsigned short*)alloc((size_t)HDIM * 256 * 2);
    unsigned short* pdW4 = (unsigned short*)alloc((size_t)HDIM * 256 * 2);
    unsigned short* pqW1 = (unsigned short*)alloc((size_t)FDIM * 256 * 2);
    unsigned short* pqW2 = (unsigned short*)alloc((size_t)HDIM * 256 * 2);
    unsigned short* pqW3 = (unsigned short*)alloc((size_t)HDIM * 256 * 2);
    unsigned short* pqW4 = (unsigned short*)alloc((size_t)HDIM * 256 * 2);

    hipMemsetAsync(pooled, 0, 512 * 4, stream);
    hipMemsetAsync(d_deg, 0, (char*)(q_deg + NQ) - (char*)d_deg, stream);

    // ---- input conversion ----
    {
        long long nd4 = (long long)ND * FDIM / 4;
        long long n4 = nd4 + (long long)NQ * FDIM / 4;
        cvt_to_bf16<<<(int)((n4 + 255) / 256), 256, 0, stream>>>(d_x, q_x, bxd, nd4, n4);
    }

    // ---- weight packing (one launch) ----
    {
        PackDesc pd;
        const float* Ws[8] = {dW1, dW2, dW3, dW4, qW1, qW2, qW3, qW4};
        unsigned short* Wps[8] = {pdW1, pdW2, pdW3, pdW4, pqW1, pqW2, pqW3, pqW4};
        int kts[8] = {4, 8, 8, 8, 4, 8, 8, 8};
        int s = 0;
        for (int i = 0; i < 8; ++i) {
            pd.W[i] = Ws[i]; pd.Wp[i] = Wps[i]; pd.KT[i] = kts[i];
            pd.start[i] = s; s += 16 * kts[i];
        }
        pd.start[8] = s;
        pack_all<<<s, 64, 0, stream>>>(pd);
    }

    // ---- CSR build ----
    const int d_eb = (ED + 255) / 256;
    const int q_eb = (EQ + 255) / 256;
    const int d_nb = (ND + 255) / 256;
    const int q_nb = (NQ + 255) / 256;
    count_deg_both<<<d_eb + q_eb, 256, 0, stream>>>(d_dst, d_deg, q_dst, q_deg, d_eb);
    scan_phase1_both<<<d_nb + q_nb, 256, 0, stream>>>(d_deg, d_rowptr, d_bsum,
                                                      q_deg, q_rowptr, q_bsum, d_nb);
    scan_phase2_both<<<2, 256, 0, stream>>>(d_bsum, d_boff, d_rowptr + ND, d_nb,
                                            q_bsum, q_boff, q_rowptr + NQ, q_nb);
    scan_phase3_both<<<d_nb + q_nb, 256, 0, stream>>>(d_rowptr, d_boff, d_cursor,
                                                      q_rowptr, q_boff, q_cursor, d_nb);
    fill_csr_both<<<d_eb + q_eb, 256, 0, stream>>>(d_src, d_dst, d_cursor, d_csrsrc,
                                                   q_src, q_dst, q_cursor, q_csrsrc, d_eb);

    // ---- GIN conv 1: agg then fused MLP (ReLU on output) ----
    const int ndb = (ND + 63) / 64;  // 782

    gin_agg_dual<FDIM><<<ND + NQ, 64, 0, stream>>>(bxd, d_rowptr, d_csrsrc, dag,
                                                   bxq, q_rowptr, q_csrsrc, qag);
    mlp_dual<FDIM><<<ndb + 1, 256, 0, stream>>>(
        dag, pdW1, db1, pdW2, db2, hd, nullptr, ndb,
        qag, pqW1, qb1, pqW2, qb2, hq, nullptr, 1);

    // ---- GIN conv 2: agg then fused MLP (pool-only, no store) ----
    gin_agg_dual<HDIM><<<ND + NQ, 64, 0, stream>>>(hd, d_rowptr, d_csrsrc, had,
                                                   hq, q_rowptr, q_csrsrc, haq);
    mlp_dual<HDIM><<<ndb + 1, 256, 0, stream>>>(
        had, pdW3, db3, pdW4, db4, nullptr, pooled + 256, ndb,
        haq, pqW3, qb3, pqW4, qb4, nullptr, pooled, 0);

    // ---- head ----
    mlp_head<<<1, 256, 0, stream>>>(pooled, lW1, lb1, lW2, lb2, lW3, lb3, (float*)d_out);
}

// Round 8
// 236.430 us; speedup vs baseline: 2.0220x; 1.1037x over previous
//
#include <hip/hip_runtime.h>
#include <hip/hip_bf16.h>

// ---------------------------------------------------------------------------
// BasicCountNet round 8:
//   - h (conv2 gather input) stored fp8 e4m3: mlp1 epilogue emits fp8 via
//     v_cvt_pk_fp8_f32; agg2 gathers 256B rows (1 dword/lane), converts via
//     v_cvt_pk_f32_fp8, accumulates fp32, writes bf16. Halves the hottest
//     random-gather traffic (147MB -> ~80MB fetch).
//   - cvt + pack + count_deg merged into one prepass kernel.
//   - 12 dispatches total.
// ---------------------------------------------------------------------------

#define NQ 64
#define EQ 512
#define ND 50000
#define ED 600000
#define FDIM 128
#define HDIM 256

typedef __attribute__((ext_vector_type(8))) short short8;
typedef __attribute__((ext_vector_type(4))) float f32x4;
typedef __attribute__((ext_vector_type(2))) float floatx2;
typedef __attribute__((ext_vector_type(4))) unsigned short us4;
typedef __attribute__((ext_vector_type(2))) unsigned short us2;

__device__ __forceinline__ unsigned short f2bf(float f) {
    union { float f; unsigned u; } v; v.f = f;
    unsigned r = v.u + 0x7FFF + ((v.u >> 16) & 1);   // RNE
    return (unsigned short)(r >> 16);
}
__device__ __forceinline__ float bf2f(unsigned short u) {
    union { unsigned u; float f; } v; v.u = ((unsigned)u) << 16;
    return v.f;
}

// ---------------- weight pack descriptor ----------------
// Wp layout: [ct(16)][kt(KT)][lane(64)][j(8)]; elem = W[kt*32+(l>>4)*8+j][ct*16+(l&15)]

struct PackDesc {
    const float* W[8];
    unsigned short* Wp[8];
    int KT[8];
    int start[9];   // in units (one unit = one (m,ct,kt), 64 lanes)
};

__device__ __forceinline__ void pack_unit(const PackDesc& pd, int unit, int l) {
    int m = 0;
    while (m < 7 && unit >= pd.start[m + 1]) ++m;
    const int local = unit - pd.start[m];
    const int KT = pd.KT[m];
    const int kt = local % KT;
    const int ct = local / KT;
    const float* W = pd.W[m];
    unsigned short* Wp = pd.Wp[m];
    const int row = kt * 32 + (l >> 4) * 8;
    const int col = ct * 16 + (l & 15);
    short8 v;
#pragma unroll
    for (int j = 0; j < 8; ++j) v[j] = (short)f2bf(W[(size_t)(row + j) * 256 + col]);
    *(short8*)(Wp + (((size_t)(ct * KT + kt)) * 64 + l) * 8) = v;
}

// ---------------- prepass: cvt(x->bf16) + pack weights + count degrees ----------------

__global__ void prepass(const float* __restrict__ xd, const float* __restrict__ xq,
                        unsigned short* __restrict__ bx, long long nd4, long long n4,
                        int cvt_b, PackDesc pd, int pack_units, int pack_b,
                        const int* __restrict__ d_dst, int* __restrict__ d_deg,
                        const int* __restrict__ q_dst, int* __restrict__ q_deg,
                        int d_eb) {
    const int b = blockIdx.x;
    const int tid = threadIdx.x;
    if (b < cvt_b) {
        long long i = (long long)b * 256 + tid;
        if (i >= n4) return;
        const float* src = (i < nd4) ? (xd + i * 4) : (xq + (i - nd4) * 4);
        float4 v = *(const float4*)src;
        us4 o;
        o[0] = f2bf(v.x); o[1] = f2bf(v.y); o[2] = f2bf(v.z); o[3] = f2bf(v.w);
        *(us4*)(bx + i * 4) = o;
    } else if (b < cvt_b + pack_b) {
        const int unit = (b - cvt_b) * 4 + (tid >> 6);
        if (unit < pack_units) pack_unit(pd, unit, tid & 63);
    } else {
        const int cb = b - cvt_b - pack_b;
        if (cb < d_eb) {
            int e = cb * 256 + tid;
            if (e < ED) atomicAdd(&d_deg[d_dst[e]], 1);
        } else {
            int e = (cb - d_eb) * 256 + tid;
            if (e < EQ) atomicAdd(&q_deg[q_dst[e]], 1);
        }
    }
}

// ---------------- CSR scan/fill (dual) ----------------

__device__ __forceinline__ void scan1_body(const int* deg, int* rowptr, int* bsum,
                                           int n, int blk) {
    __shared__ int sh[256];
    const int t = threadIdx.x;
    const int i = blk * 256 + t;
    const int v = (i < n) ? deg[i] : 0;
    sh[t] = v;
    __syncthreads();
    for (int off = 1; off < 256; off <<= 1) {
        int x = (t >= off) ? sh[t - off] : 0;
        __syncthreads();
        sh[t] += x;
        __syncthreads();
    }
    if (i < n) rowptr[i] = sh[t] - v;
    if (t == 255) bsum[blk] = sh[255];
}

__global__ void scan_phase1_both(const int* __restrict__ d_deg, int* __restrict__ d_rowptr,
                                 int* __restrict__ d_bsum,
                                 const int* __restrict__ q_deg, int* __restrict__ q_rowptr,
                                 int* __restrict__ q_bsum, int dblocks) {
    int b = blockIdx.x;
    if (b < dblocks) scan1_body(d_deg, d_rowptr, d_bsum, ND, b);
    else             scan1_body(q_deg, q_rowptr, q_bsum, NQ, b - dblocks);
}

__device__ __forceinline__ void scan2_body(const int* bsum, int* boff, int* rowptr_n, int nb) {
    __shared__ int sh[256];
    const int t = threadIdx.x;
    const int v = (t < nb) ? bsum[t] : 0;
    sh[t] = v;
    __syncthreads();
    for (int off = 1; off < 256; off <<= 1) {
        int x = (t >= off) ? sh[t - off] : 0;
        __syncthreads();
        sh[t] += x;
        __syncthreads();
    }
    if (t < nb) boff[t] = sh[t] - v;
    if (t == 255) *rowptr_n = sh[255];
}

__global__ void scan_phase2_both(const int* __restrict__ d_bsum, int* __restrict__ d_boff,
                                 int* __restrict__ d_rowptr_n, int d_nb,
                                 const int* __restrict__ q_bsum, int* __restrict__ q_boff,
                                 int* __restrict__ q_rowptr_n, int q_nb) {
    if (blockIdx.x == 0) scan2_body(d_bsum, d_boff, d_rowptr_n, d_nb);
    else                 scan2_body(q_bsum, q_boff, q_rowptr_n, q_nb);
}

__global__ void scan_phase3_both(int* __restrict__ d_rowptr, const int* __restrict__ d_boff,
                                 int* __restrict__ d_cursor,
                                 int* __restrict__ q_rowptr, const int* __restrict__ q_boff,
                                 int* __restrict__ q_cursor, int dblocks) {
    int b = blockIdx.x;
    if (b < dblocks) {
        int i = b * 256 + threadIdx.x;
        if (i < ND) {
            int r = d_rowptr[i] + d_boff[b];
            d_rowptr[i] = r; d_cursor[i] = r;
        }
    } else {
        int i = (b - dblocks) * 256 + threadIdx.x;
        if (i < NQ) {
            int r = q_rowptr[i] + q_boff[b - dblocks];
            q_rowptr[i] = r; q_cursor[i] = r;
        }
    }
}

__global__ void fill_csr_both(const int* __restrict__ d_src, const int* __restrict__ d_dst,
                              int* __restrict__ d_cursor, int* __restrict__ d_csrsrc,
                              const int* __restrict__ q_src, const int* __restrict__ q_dst,
                              int* __restrict__ q_cursor, int* __restrict__ q_csrsrc,
                              int dblocks) {
    int b = blockIdx.x;
    if (b < dblocks) {
        int e = b * 256 + threadIdx.x;
        if (e < ED) {
            int p = atomicAdd(&d_cursor[d_dst[e]], 1);
            d_csrsrc[p] = d_src[e];
        }
    } else {
        int e = (b - dblocks) * 256 + threadIdx.x;
        if (e < EQ) {
            int p = atomicAdd(&q_cursor[q_dst[e]], 1);
            q_csrsrc[p] = q_src[e];
        }
    }
}

// ---------------- aggregation, bf16 in / bf16 out (conv1) ----------------

template <int F>
__global__ void gin_agg_dual(const unsigned short* __restrict__ xd, const int* __restrict__ rpd,
                             const int* __restrict__ csd, unsigned short* __restrict__ od,
                             const unsigned short* __restrict__ xq, const int* __restrict__ rpq,
                             const int* __restrict__ csq, unsigned short* __restrict__ oq) {
    constexpr int V = F / 64;
    const unsigned short* x; const int* rowptr; const int* csr; unsigned short* out; int node;
    if ((int)blockIdx.x < ND) { x = xd; rowptr = rpd; csr = csd; out = od; node = blockIdx.x; }
    else { x = xq; rowptr = rpq; csr = csq; out = oq; node = blockIdx.x - ND; }

    const int t = threadIdx.x;
    const int beg = rowptr[node];
    const int end = rowptr[node + 1];

    float acc[V];
    {
        const unsigned short* p = x + (size_t)node * F + t * V;
        if constexpr (V == 4) {
            us4 v = *(const us4*)p;
#pragma unroll
            for (int i = 0; i < 4; ++i) acc[i] = bf2f(v[i]);
        } else {
            us2 v = *(const us2*)p;
            acc[0] = bf2f(v[0]); acc[1] = bf2f(v[1]);
        }
    }
    int j = beg;
    for (; j + 1 < end; j += 2) {
        const unsigned short* p0 = x + (size_t)csr[j] * F + t * V;
        const unsigned short* p1 = x + (size_t)csr[j + 1] * F + t * V;
        if constexpr (V == 4) {
            us4 v0 = *(const us4*)p0;
            us4 v1 = *(const us4*)p1;
#pragma unroll
            for (int i = 0; i < 4; ++i) acc[i] += bf2f(v0[i]) + bf2f(v1[i]);
        } else {
            us2 v0 = *(const us2*)p0;
            us2 v1 = *(const us2*)p1;
            acc[0] += bf2f(v0[0]) + bf2f(v1[0]);
            acc[1] += bf2f(v0[1]) + bf2f(v1[1]);
        }
    }
    if (j < end) {
        const unsigned short* p0 = x + (size_t)csr[j] * F + t * V;
        if constexpr (V == 4) {
            us4 v0 = *(const us4*)p0;
#pragma unroll
            for (int i = 0; i < 4; ++i) acc[i] += bf2f(v0[i]);
        } else {
            us2 v0 = *(const us2*)p0;
            acc[0] += bf2f(v0[0]); acc[1] += bf2f(v0[1]);
        }
    }
    unsigned short* po = out + (size_t)node * F + t * V;
    if constexpr (V == 4) {
        us4 r;
#pragma unroll
        for (int i = 0; i < 4; ++i) r[i] = f2bf(acc[i]);
        *(us4*)po = r;
    } else {
        us2 r; r[0] = f2bf(acc[0]); r[1] = f2bf(acc[1]);
        *(us2*)po = r;
    }
}

// ---------------- aggregation, fp8 in / bf16 out (conv2, F=256) ----------------
// per lane: 4 fp8 bytes = 1 dword; hw cvt_pk_f32_fp8; fp32 accumulate

__global__ void gin_agg_f8_dual(const unsigned char* __restrict__ xd, const int* __restrict__ rpd,
                                const int* __restrict__ csd, unsigned short* __restrict__ od,
                                const unsigned char* __restrict__ xq, const int* __restrict__ rpq,
                                const int* __restrict__ csq, unsigned short* __restrict__ oq) {
    const unsigned char* x; const int* rowptr; const int* csr; unsigned short* out; int node;
    if ((int)blockIdx.x < ND) { x = xd; rowptr = rpd; csr = csd; out = od; node = blockIdx.x; }
    else { x = xq; rowptr = rpq; csr = csq; out = oq; node = blockIdx.x - ND; }

    const int t = threadIdx.x;
    const int beg = rowptr[node];
    const int end = rowptr[node + 1];

    float a0, a1, a2, a3;
    {
        const unsigned w = *(const unsigned*)(x + (size_t)node * 256 + t * 4);
        floatx2 lo = __builtin_amdgcn_cvt_pk_f32_fp8((int)w, false);
        floatx2 hi = __builtin_amdgcn_cvt_pk_f32_fp8((int)w, true);
        a0 = lo[0]; a1 = lo[1]; a2 = hi[0]; a3 = hi[1];
    }
    int j = beg;
    for (; j + 1 < end; j += 2) {
        const unsigned w0 = *(const unsigned*)(x + (size_t)csr[j] * 256 + t * 4);
        const unsigned w1 = *(const unsigned*)(x + (size_t)csr[j + 1] * 256 + t * 4);
        floatx2 l0 = __builtin_amdgcn_cvt_pk_f32_fp8((int)w0, false);
        floatx2 h0 = __builtin_amdgcn_cvt_pk_f32_fp8((int)w0, true);
        floatx2 l1 = __builtin_amdgcn_cvt_pk_f32_fp8((int)w1, false);
        floatx2 h1 = __builtin_amdgcn_cvt_pk_f32_fp8((int)w1, true);
        a0 += l0[0] + l1[0]; a1 += l0[1] + l1[1];
        a2 += h0[0] + h1[0]; a3 += h0[1] + h1[1];
    }
    if (j < end) {
        const unsigned w0 = *(const unsigned*)(x + (size_t)csr[j] * 256 + t * 4);
        floatx2 l0 = __builtin_amdgcn_cvt_pk_f32_fp8((int)w0, false);
        floatx2 h0 = __builtin_amdgcn_cvt_pk_f32_fp8((int)w0, true);
        a0 += l0[0]; a1 += l0[1]; a2 += h0[0]; a3 += h0[1];
    }
    us4 r;
    r[0] = f2bf(a0); r[1] = f2bf(a1); r[2] = f2bf(a2); r[3] = f2bf(a3);
    *(us4*)(out + (size_t)node * 256 + t * 4) = r;
}

// ---------------- fused MLP: out = [relu?]( relu(A @ W1 + b1) @ W2 + b2 ) ----------------
// Block = 64 rows x 256 cols, 4 waves. Dual: data blocks [0,ndb), query block ndb.
// C8 non-null -> store fp8; else C non-null -> store bf16; pool optional.

template <int KIN>
__global__ __launch_bounds__(256) void mlp_dual(
    const unsigned short* __restrict__ Ad,
    const unsigned short* __restrict__ W1pd, const float* __restrict__ b1d,
    const unsigned short* __restrict__ W2pd, const float* __restrict__ b2d,
    unsigned char* __restrict__ C8d, float* __restrict__ poold, int ndb,
    const unsigned short* __restrict__ Aq,
    const unsigned short* __restrict__ W1pq, const float* __restrict__ b1q,
    const unsigned short* __restrict__ W2pq, const float* __restrict__ b2q,
    unsigned char* __restrict__ C8q, float* __restrict__ poolq,
    int relu_out) {
    constexpr int KT1 = KIN / 32;
    __shared__ __align__(16) unsigned short lds[64 * 256];  // 32 KB, A then T1

    const unsigned short* A; const unsigned short* W1p; const float* b1;
    const unsigned short* W2p; const float* b2;
    unsigned char* C8; float* pool; int row0, N;
    if ((int)blockIdx.x < ndb) {
        A = Ad; W1p = W1pd; b1 = b1d; W2p = W2pd; b2 = b2d;
        C8 = C8d; pool = poold; row0 = blockIdx.x * 64; N = ND;
    } else {
        A = Aq; W1p = W1pq; b1 = b1q; W2p = W2pq; b2 = b2q;
        C8 = C8q; pool = poolq; row0 = 0; N = NQ;
    }

    const int tid = threadIdx.x;
    const int lane = tid & 63;
    const int wv = tid >> 6;
    const int lrow = lane & 15;
    const int lk2 = (lane >> 4) * 8;
    const int nrows = (N - row0 < 64) ? (N - row0) : 64;

    // ---- stage A: linear coalesced bf16 loads, swizzled 16B LDS writes ----
    for (int idx = tid; idx < nrows * (KIN / 8); idx += 256) {
        const int r = idx / (KIN / 8);
        const int k8 = (idx % (KIN / 8)) * 8;
        short8 v = *(const short8*)(A + (size_t)(row0 + r) * KIN + k8);
        unsigned byte = (unsigned)((r * KIN + k8) * 2) ^ (unsigned)((r & 7) << 4);
        *(short8*)((char*)lds + byte) = v;
    }
    __syncthreads();

    // ---- pass 1: T1 = relu(A @ W1 + b1) ----
    f32x4 acc1[4][4];
#pragma unroll
    for (int fm = 0; fm < 4; ++fm)
#pragma unroll
        for (int fn = 0; fn < 4; ++fn) acc1[fm][fn] = (f32x4)(0.f);

    const unsigned short* W1Base = W1p + ((size_t)(wv * 4) * KT1 * 64 + lane) * 8;
    for (int kt = 0; kt < KT1; ++kt) {
        short8 a[4], bf[4];
#pragma unroll
        for (int fm = 0; fm < 4; ++fm) {
            const int r = fm * 16 + lrow;
            unsigned byte = (unsigned)((r * KIN + kt * 32 + lk2) * 2) ^ (unsigned)((r & 7) << 4);
            a[fm] = *(const short8*)((const char*)lds + byte);
        }
#pragma unroll
        for (int fn = 0; fn < 4; ++fn)
            bf[fn] = *(const short8*)(W1Base + ((size_t)fn * KT1 + kt) * 64 * 8);
#pragma unroll
        for (int fm = 0; fm < 4; ++fm)
#pragma unroll
            for (int fn = 0; fn < 4; ++fn)
                acc1[fm][fn] = __builtin_amdgcn_mfma_f32_16x16x32_bf16(
                    a[fm], bf[fn], acc1[fm][fn], 0, 0, 0);
    }
    __syncthreads();  // all pass-1 LDS reads done before T1 overwrites

    // ---- T1 tile (bias + relu, bf16) into lds, stride 256, same swizzle ----
#pragma unroll
    for (int fn = 0; fn < 4; ++fn) {
        const int col = wv * 64 + fn * 16 + lrow;
        const float bv = b1[col];
#pragma unroll
        for (int fm = 0; fm < 4; ++fm) {
            const int rbase = fm * 16 + (lane >> 4) * 4;
#pragma unroll
            for (int r = 0; r < 4; ++r) {
                const int row = rbase + r;
                const float v = fmaxf(acc1[fm][fn][r] + bv, 0.f);
                unsigned byte = (unsigned)((row * 256 + col) * 2) ^ (unsigned)((row & 7) << 4);
                *(unsigned short*)((char*)lds + byte) = f2bf(v);
            }
        }
    }
    __syncthreads();

    // ---- pass 2: out = T1 @ W2 + b2 ----
    f32x4 acc2[4][4];
#pragma unroll
    for (int fm = 0; fm < 4; ++fm)
#pragma unroll
        for (int fn = 0; fn < 4; ++fn) acc2[fm][fn] = (f32x4)(0.f);

    const unsigned short* W2Base = W2p + ((size_t)(wv * 4) * 8 * 64 + lane) * 8;
    for (int kt = 0; kt < 8; ++kt) {
        short8 a[4], bf[4];
#pragma unroll
        for (int fm = 0; fm < 4; ++fm) {
            const int r = fm * 16 + lrow;
            unsigned byte = (unsigned)((r * 256 + kt * 32 + lk2) * 2) ^ (unsigned)((r & 7) << 4);
            a[fm] = *(const short8*)((const char*)lds + byte);
        }
#pragma unroll
        for (int fn = 0; fn < 4; ++fn)
            bf[fn] = *(const short8*)(W2Base + ((size_t)fn * 8 + kt) * 64 * 8);
#pragma unroll
        for (int fm = 0; fm < 4; ++fm)
#pragma unroll
            for (int fn = 0; fn < 4; ++fn)
                acc2[fm][fn] = __builtin_amdgcn_mfma_f32_16x16x32_bf16(
                    a[fm], bf[fn], acc2[fm][fn], 0, 0, 0);
    }

    // ---- epilogue: bias2 (+relu_out), store fp8 C8 / pool colsum ----
#pragma unroll
    for (int fn = 0; fn < 4; ++fn) {
        const int col = wv * 64 + fn * 16 + lrow;
        const float bv = b2[col];
        float ps = 0.f;
#pragma unroll
        for (int fm = 0; fm < 4; ++fm) {
            const int rbase = row0 + fm * 16 + (lane >> 4) * 4;
#pragma unroll
            for (int r = 0; r < 4; ++r) {
                const int row = rbase + r;
                if (row < N) {
                    float v = acc2[fm][fn][r] + bv;
                    if (relu_out) v = fmaxf(v, 0.f);
                    if (C8) {
                        unsigned p = (unsigned)__builtin_amdgcn_cvt_pk_fp8_f32(v, v, 0, false);
                        C8[(size_t)row * 256 + col] = (unsigned char)(p & 0xff);
                    }
                    ps += v;
                }
            }
        }
        if (pool) {
            ps += __shfl_xor(ps, 16);
            ps += __shfl_xor(ps, 32);
            if ((lane >> 4) == 0) atomicAdd(&pool[col], ps);
        }
    }
}

// ---------------- head ----------------

__global__ void mlp_head(const float* __restrict__ pooled,
                         const float* __restrict__ lW1, const float* __restrict__ lb1,
                         const float* __restrict__ lW2, const float* __restrict__ lb2,
                         const float* __restrict__ lW3, const float* __restrict__ lb3,
                         float* __restrict__ out) {
    __shared__ float h0[512];
    __shared__ float h1[256];
    __shared__ float h2[128];
    const int t = threadIdx.x;  // 256 threads
    h0[t] = pooled[t];
    h0[t + 256] = pooled[t + 256];
    __syncthreads();

    float acc = lb1[t];
    for (int k = 0; k < 512; ++k) acc += h0[k] * lW1[k * 256 + t];
    h1[t] = fmaxf(acc, 0.f);
    __syncthreads();

    if (t < 128) {
        float a = lb2[t];
        for (int k = 0; k < 256; ++k) a += h1[k] * lW2[k * 128 + t];
        h2[t] = fmaxf(a, 0.f);
    }
    __syncthreads();

    if (t < 8) {
        float a = lb3[t];
        for (int k = 0; k < 128; ++k) a += h2[k] * lW3[k * 8 + t];
        out[t] = fmaxf(a, 0.f);
    }
}

// ---------------------------------------------------------------------------

extern "C" void kernel_launch(void* const* d_in, const int* in_sizes, int n_in,
                              void* d_out, int out_size, void* d_ws, size_t ws_size,
                              hipStream_t stream) {
    const float* q_x  = (const float*)d_in[0];
    const float* d_x  = (const float*)d_in[1];
    const int*   q_el = (const int*)d_in[2];
    const int*   d_el = (const int*)d_in[3];
    const float* qW1 = (const float*)d_in[4];  const float* qb1 = (const float*)d_in[5];
    const float* qW2 = (const float*)d_in[6];  const float* qb2 = (const float*)d_in[7];
    const float* qW3 = (const float*)d_in[8];  const float* qb3 = (const float*)d_in[9];
    const float* qW4 = (const float*)d_in[10]; const float* qb4 = (const float*)d_in[11];
    const float* dW1 = (const float*)d_in[12]; const float* db1 = (const float*)d_in[13];
    const float* dW2 = (const float*)d_in[14]; const float* db2 = (const float*)d_in[15];
    const float* dW3 = (const float*)d_in[16]; const float* db3 = (const float*)d_in[17];
    const float* dW4 = (const float*)d_in[18]; const float* db4 = (const float*)d_in[19];
    const float* lW1 = (const float*)d_in[20]; const float* lb1 = (const float*)d_in[21];
    const float* lW2 = (const float*)d_in[22]; const float* lb2 = (const float*)d_in[23];
    const float* lW3 = (const float*)d_in[24]; const float* lb3 = (const float*)d_in[25];
    (void)in_sizes; (void)n_in; (void)out_size; (void)ws_size;

    const int* q_src = q_el;  const int* q_dst = q_el + EQ;
    const int* d_src = d_el;  const int* d_dst = d_el + ED;

    // ---- workspace layout ----
    char* wsb = (char*)d_ws;
    size_t off = 0;
    auto alloc = [&](size_t bytes) { void* p = wsb + off; off += (bytes + 255) & ~(size_t)255; return p; };

    unsigned short* bxd = (unsigned short*)alloc((size_t)ND * FDIM * 2);  // bf16 d_x
    unsigned short* bxq = (unsigned short*)alloc((size_t)NQ * FDIM * 2);  // adjacent
    unsigned short* dag = (unsigned short*)alloc((size_t)ND * FDIM * 2);  // agg1 out (data)
    unsigned short* qag = (unsigned short*)alloc((size_t)NQ * FDIM * 2);
    unsigned char*  h8d = (unsigned char*)alloc((size_t)ND * HDIM);      // conv1 out, fp8
    unsigned char*  h8q = (unsigned char*)alloc((size_t)NQ * HDIM);
    unsigned short* had = (unsigned short*)alloc((size_t)ND * HDIM * 2);  // agg2 out, bf16
    unsigned short* haq = (unsigned short*)alloc((size_t)NQ * HDIM * 2);
    float* pooled = (float*)alloc(512 * 4);
    int* d_deg    = (int*)alloc((size_t)ND * 4);
    int* q_deg    = (int*)alloc((size_t)NQ * 4);   // adjacent to d_deg (one memset)
    int* d_rowptr = (int*)alloc((size_t)(ND + 1) * 4);
    int* d_cursor = (int*)alloc((size_t)ND * 4);
    int* d_csrsrc = (int*)alloc((size_t)ED * 4);
    int* d_bsum   = (int*)alloc(256 * 4);
    int* d_boff   = (int*)alloc(256 * 4);
    int* q_rowptr = (int*)alloc((size_t)(NQ + 1) * 4);
    int* q_cursor = (int*)alloc((size_t)NQ * 4);
    int* q_csrsrc = (int*)alloc((size_t)EQ * 4);
    int* q_bsum   = (int*)alloc(256 * 4);
    int* q_boff   = (int*)alloc(256 * 4);
    unsigned short* pdW1 = (unsigned short*)alloc((size_t)FDIM * 256 * 2);
    unsigned short* pdW2 = (unsigned short*)alloc((size_t)HDIM * 256 * 2);
    unsigned short* pdW3 = (unsigned short*)alloc((size_t)HDIM * 256 * 2);
    unsigned short* pdW4 = (unsigned short*)alloc((size_t)HDIM * 256 * 2);
    unsigned short* pqW1 = (unsigned short*)alloc((size_t)FDIM * 256 * 2);
    unsigned short* pqW2 = (unsigned short*)alloc((size_t)HDIM * 256 * 2);
    unsigned short* pqW3 = (unsigned short*)alloc((size_t)HDIM * 256 * 2);
    unsigned short* pqW4 = (unsigned short*)alloc((size_t)HDIM * 256 * 2);

    hipMemsetAsync(pooled, 0, 512 * 4, stream);
    hipMemsetAsync(d_deg, 0, (char*)(q_deg + NQ) - (char*)d_deg, stream);

    // ---- prepass: cvt + pack + count ----
    const int d_eb = (ED + 255) / 256;   // 2344
    const int q_eb = (EQ + 255) / 256;   // 2
    const int d_nb = (ND + 255) / 256;   // 196
    const int q_nb = (NQ + 255) / 256;   // 1
    {
        PackDesc pd;
        const float* Ws[8] = {dW1, dW2, dW3, dW4, qW1, qW2, qW3, qW4};
        unsigned short* Wps[8] = {pdW1, pdW2, pdW3, pdW4, pqW1, pqW2, pqW3, pqW4};
        int kts[8] = {4, 8, 8, 8, 4, 8, 8, 8};
        int s = 0;
        for (int i = 0; i < 8; ++i) {
            pd.W[i] = Ws[i]; pd.Wp[i] = Wps[i]; pd.KT[i] = kts[i];
            pd.start[i] = s; s += 16 * kts[i];
        }
        pd.start[8] = s;                       // 896 units
        const int pack_units = s;
        const int pack_b = (s + 3) / 4;        // 224 blocks (4 units of 64 lanes each)
        long long nd4 = (long long)ND * FDIM / 4;
        long long n4 = nd4 + (long long)NQ * FDIM / 4;
        const int cvt_b = (int)((n4 + 255) / 256);
        prepass<<<cvt_b + pack_b + d_eb + q_eb, 256, 0, stream>>>(
            d_x, q_x, bxd, nd4, n4, cvt_b, pd, pack_units, pack_b,
            d_dst, d_deg, q_dst, q_deg, d_eb);
    }

    // ---- CSR scan + fill ----
    scan_phase1_both<<<d_nb + q_nb, 256, 0, stream>>>(d_deg, d_rowptr, d_bsum,
                                                      q_deg, q_rowptr, q_bsum, d_nb);
    scan_phase2_both<<<2, 256, 0, stream>>>(d_bsum, d_boff, d_rowptr + ND, d_nb,
                                            q_bsum, q_boff, q_rowptr + NQ, q_nb);
    scan_phase3_both<<<d_nb + q_nb, 256, 0, stream>>>(d_rowptr, d_boff, d_cursor,
                                                      q_rowptr, q_boff, q_cursor, d_nb);
    fill_csr_both<<<d_eb + q_eb, 256, 0, stream>>>(d_src, d_dst, d_cursor, d_csrsrc,
                                                   q_src, q_dst, q_cursor, q_csrsrc, d_eb);

    // ---- GIN conv 1: agg (bf16) then fused MLP -> h fp8 ----
    const int ndb = (ND + 63) / 64;  // 782

    gin_agg_dual<FDIM><<<ND + NQ, 64, 0, stream>>>(bxd, d_rowptr, d_csrsrc, dag,
                                                   bxq, q_rowptr, q_csrsrc, qag);
    mlp_dual<FDIM><<<ndb + 1, 256, 0, stream>>>(
        dag, pdW1, db1, pdW2, db2, h8d, nullptr, ndb,
        qag, pqW1, qb1, pqW2, qb2, h8q, nullptr, 1);

    // ---- GIN conv 2: agg (fp8 gather) then fused MLP (pool-only) ----
    gin_agg_f8_dual<<<ND + NQ, 64, 0, stream>>>(h8d, d_rowptr, d_csrsrc, had,
                                                h8q, q_rowptr, q_csrsrc, haq);
    mlp_dual<HDIM><<<ndb + 1, 256, 0, stream>>>(
        had, pdW3, db3, pdW4, db4, nullptr, pooled + 256, ndb,
        haq, pqW3, qb3, pqW4, qb4, nullptr, pooled, 0);

    // ---- head ----
    mlp_head<<<1, 256, 0, stream>>>(pooled, lW1, lb1, lW2, lb2, lW3, lb3, (float*)d_out);
}